// Round 1
// baseline (257.744 us; speedup 1.0000x reference)
//
#include <hip/hip_runtime.h>

#define TSEQ 2048
#define DDIM 1024
#define HSZ  64
#define NB   4
#define NROWS (NB * TSEQ)

// ---------------------------------------------------------------------------
// Kernel 1: fused QKV projection (fp32).
// grid (NROWS/32, 3), block 256. y=0: Wk->kbuf, y=1: Wq->qbuf (x8), y=2: Wv->vbuf
// BM=32 rows, BN=64 cols, BK=32. Per-thread 2x4 acc. Pads of 33 words kill
// bank conflicts (column index advances 1 per lane: c = tx + 16*j).
// ---------------------------------------------------------------------------
__global__ __launch_bounds__(256) void qkv_proj_kernel(
    const float* __restrict__ x,
    const float* __restrict__ Wk,
    const float* __restrict__ Wq,
    const float* __restrict__ Wv,
    float* __restrict__ kbuf, float* __restrict__ qbuf, float* __restrict__ vbuf)
{
    __shared__ float xs[32][33];
    __shared__ float wsh[64][33];

    const float* w; float* o; float scale;
    if (blockIdx.y == 0)      { w = Wk; o = kbuf; scale = 1.0f; }
    else if (blockIdx.y == 1) { w = Wq; o = qbuf; scale = 8.0f; }  // fold sqrt(HS) bug-faithful scale into q
    else                      { w = Wv; o = vbuf; scale = 1.0f; }

    const int tid = threadIdx.x;
    const int tx = tid & 15;          // column lane: cols tx, tx+16, tx+32, tx+48
    const int ty = tid >> 4;          // 0..15 -> rows ty*2, ty*2+1
    const int r0 = ty * 2;
    const long rb = (long)blockIdx.x * 32;

    float acc[2][4] = {};

    for (int kk = 0; kk < DDIM; kk += 32) {
        // x tile: 32x32, one float4 per thread
        {
            int row = tid >> 3, c4 = (tid & 7) * 4;
            float4 v4 = *(const float4*)(x + (rb + row) * DDIM + kk + c4);
            xs[row][c4+0] = v4.x; xs[row][c4+1] = v4.y;
            xs[row][c4+2] = v4.z; xs[row][c4+3] = v4.w;
        }
        // w tile: 64x32, two float4 per thread
        #pragma unroll
        for (int u = 0; u < 2; ++u) {
            int idx = tid + u * 256;
            int row = idx >> 3, c4 = (idx & 7) * 4;
            float4 v4 = *(const float4*)(w + (long)row * DDIM + kk + c4);
            wsh[row][c4+0] = v4.x; wsh[row][c4+1] = v4.y;
            wsh[row][c4+2] = v4.z; wsh[row][c4+3] = v4.w;
        }
        __syncthreads();

        #pragma unroll 8
        for (int k = 0; k < 32; ++k) {
            float a0 = xs[r0+0][k];
            float a1 = xs[r0+1][k];
            float b0 = wsh[tx +  0][k];
            float b1 = wsh[tx + 16][k];
            float b2 = wsh[tx + 32][k];
            float b3 = wsh[tx + 48][k];
            acc[0][0] += a0*b0; acc[0][1] += a0*b1; acc[0][2] += a0*b2; acc[0][3] += a0*b3;
            acc[1][0] += a1*b0; acc[1][1] += a1*b1; acc[1][2] += a1*b2; acc[1][3] += a1*b3;
        }
        __syncthreads();
    }

    #pragma unroll
    for (int i = 0; i < 2; ++i) {
        const long orow = (rb + r0 + i) * HSZ;
        o[orow + tx +  0] = acc[i][0] * scale;
        o[orow + tx + 16] = acc[i][1] * scale;
        o[orow + tx + 32] = acc[i][2] * scale;
        o[orow + tx + 48] = acc[i][3] * scale;
    }
}

// ---------------------------------------------------------------------------
// Kernel 2: causal flash attention (fp32). q is pre-scaled by 8.
// grid 512 (= NB * T/16), block 256. BQ=16 q-rows, BK=128 keys per step.
// Heavy tiles dispatched first (work ~ tile index) for load balance.
// LDS ~77KB -> 2 blocks/CU.
// ---------------------------------------------------------------------------
__global__ __launch_bounds__(256) void attn_kernel(
    const float* __restrict__ q, const float* __restrict__ k,
    const float* __restrict__ v, float* __restrict__ out)
{
    __shared__ float qs[16][65];
    __shared__ float ks[128][65];
    __shared__ float vs[128][64];
    __shared__ float ps[16][132];
    __shared__ float m_s[16], l_s[16], f_s[16];

    const int tid   = threadIdx.x;
    const int bid   = blockIdx.x;
    const int batch = bid & 3;
    const int tile  = 127 - (bid >> 2);   // heaviest (most k-steps) first
    const int qb0   = tile * 16;
    const long base = (long)batch * TSEQ;

    // Q tile: 16x64, one float4 per thread
    {
        int row = tid >> 4, c4 = (tid & 15) * 4;
        float4 v4 = *(const float4*)(q + (base + qb0 + row) * HSZ + c4);
        qs[row][c4+0] = v4.x; qs[row][c4+1] = v4.y;
        qs[row][c4+2] = v4.z; qs[row][c4+3] = v4.w;
    }
    if (tid < 16) { m_s[tid] = -1e30f; l_s[tid] = 0.0f; }

    // S-phase mapping: 8 row-pairs (ty) x 32 column lanes (tx); cols tx+32*j
    const int tx  = tid & 31, ty = tid >> 5;
    const int sr0 = ty * 2;
    // PV/O mapping: row = tid>>4 (16 rows), d0 = (tid&15)*4
    const int orow = tid >> 4, od0 = (tid & 15) * 4;
    float o0 = 0.f, o1 = 0.f, o2 = 0.f, o3 = 0.f;

    const int nsteps = (qb0 + 16 + 127) >> 7;
    for (int s = 0; s < nsteps; ++s) {
        const int jb = s << 7;
        // load K,V tiles: 128x64 each, 8 float4 per thread per tile
        #pragma unroll
        for (int u = 0; u < 8; ++u) {
            int idx = tid + u * 256;
            int row = idx >> 4, c4 = (idx & 15) * 4;
            float4 kv = *(const float4*)(k + (base + jb + row) * HSZ + c4);
            ks[row][c4+0] = kv.x; ks[row][c4+1] = kv.y;
            ks[row][c4+2] = kv.z; ks[row][c4+3] = kv.w;
            float4 vv = *(const float4*)(v + (base + jb + row) * HSZ + c4);
            *(float4*)&vs[row][c4] = vv;
        }
        __syncthreads();

        // S = Q K^T  (2 rows x 4 cols per thread; cols tx, tx+32, tx+64, tx+96)
        float sa[2][4] = {};
        #pragma unroll 16
        for (int d = 0; d < 64; ++d) {
            float a0 = qs[sr0+0][d];
            float a1 = qs[sr0+1][d];
            float b0 = ks[tx +  0][d];
            float b1 = ks[tx + 32][d];
            float b2 = ks[tx + 64][d];
            float b3 = ks[tx + 96][d];
            sa[0][0] += a0*b0; sa[0][1] += a0*b1; sa[0][2] += a0*b2; sa[0][3] += a0*b3;
            sa[1][0] += a1*b0; sa[1][1] += a1*b1; sa[1][2] += a1*b2; sa[1][3] += a1*b3;
        }
        // causal mask: only the final step straddles the diagonal
        if (s == nsteps - 1) {
            #pragma unroll
            for (int i = 0; i < 2; ++i) {
                #pragma unroll
                for (int j = 0; j < 4; ++j) {
                    int kg = jb + tx + 32*j;
                    if (kg > qb0 + sr0 + i) sa[i][j] = -1e30f;
                }
            }
        }
        // online softmax per row (32 lanes per row; row stats via shfl_xor)
        #pragma unroll
        for (int i = 0; i < 2; ++i) {
            float mx = fmaxf(fmaxf(sa[i][0], sa[i][1]), fmaxf(sa[i][2], sa[i][3]));
            #pragma unroll
            for (int off = 1; off < 32; off <<= 1) mx = fmaxf(mx, __shfl_xor(mx, off));
            float mold = m_s[sr0 + i];           // read-before-write within same wave: safe
            float mnew = fmaxf(mold, mx);
            float p0 = __expf(sa[i][0] - mnew);
            float p1 = __expf(sa[i][1] - mnew);
            float p2 = __expf(sa[i][2] - mnew);
            float p3 = __expf(sa[i][3] - mnew);
            ps[sr0+i][tx +  0] = p0;
            ps[sr0+i][tx + 32] = p1;
            ps[sr0+i][tx + 64] = p2;
            ps[sr0+i][tx + 96] = p3;
            float rs = p0 + p1 + p2 + p3;
            #pragma unroll
            for (int off = 1; off < 32; off <<= 1) rs += __shfl_xor(rs, off);
            if (tx == 0) {
                float f = __expf(mold - mnew);
                f_s[sr0+i] = f;
                m_s[sr0+i] = mnew;
                l_s[sr0+i] = l_s[sr0+i] * f + rs;
            }
        }
        __syncthreads();

        // O = O*f + P V
        float f = f_s[orow];
        o0 *= f; o1 *= f; o2 *= f; o3 *= f;
        #pragma unroll 16
        for (int kk = 0; kk < 128; ++kk) {
            float pv = ps[orow][kk];
            float4 vv = *(const float4*)&vs[kk][od0];
            o0 += pv * vv.x; o1 += pv * vv.y; o2 += pv * vv.z; o3 += pv * vv.w;
        }
        __syncthreads();   // protects ks/vs/ps for next iteration's loads
    }

    float linv = 1.0f / l_s[orow];
    float4 r = make_float4(o0*linv, o1*linv, o2*linv, o3*linv);
    *(float4*)(out + (base + qb0 + orow) * HSZ + od0) = r;
}

// ---------------------------------------------------------------------------
extern "C" void kernel_launch(void* const* d_in, const int* in_sizes, int n_in,
                              void* d_out, int out_size, void* d_ws, size_t ws_size,
                              hipStream_t stream) {
    const float* x  = (const float*)d_in[0];
    const float* Wk = (const float*)d_in[1];
    const float* Wq = (const float*)d_in[2];
    const float* Wv = (const float*)d_in[3];
    float* out = (float*)d_out;

    float* ws   = (float*)d_ws;
    float* kbuf = ws;                       // [NROWS][64]
    float* qbuf = ws + (size_t)NROWS * HSZ; // [NROWS][64] (pre-scaled by 8)
    float* vbuf = ws + (size_t)2 * NROWS * HSZ;

    dim3 g1(NROWS / 32, 3);
    qkv_proj_kernel<<<g1, 256, 0, stream>>>(x, Wk, Wq, Wv, kbuf, qbuf, vbuf);

    attn_kernel<<<NB * (TSEQ / 16), 256, 0, stream>>>(qbuf, kbuf, vbuf, out);
}

// Round 2
// 151.904 us; speedup vs baseline: 1.6968x; 1.6968x over previous
//
#include <hip/hip_runtime.h>

#define TSEQ 2048
#define DDIM 1024
#define HSZ  64
#define NB   4
#define NROWS (NB * TSEQ)

typedef short bf16x8 __attribute__((ext_vector_type(8)));
typedef short s16x4  __attribute__((ext_vector_type(4)));
typedef float f32x4  __attribute__((ext_vector_type(4)));

#define MFMA16(a, b, c) __builtin_amdgcn_mfma_f32_16x16x32_bf16((a), (b), (c), 0, 0, 0)

// Split fp32 into bf16 hi + bf16 lo (truncation; lo captures the remainder).
__device__ inline void split_bf16(float f, short& hi, short& lo) {
    unsigned u = __builtin_bit_cast(unsigned, f);
    hi = (short)(u >> 16);
    float fh = __builtin_bit_cast(float, u & 0xffff0000u);
    float fl = f - fh;                       // exact in fp32
    lo = (short)(__builtin_bit_cast(unsigned, fl) >> 16);
}

// ---------------------------------------------------------------------------
// Kernel 0: split Wk/Wq/Wv (fp32 [64][1024]) into bf16 hi/lo -> wbhi/wblo [3][64][1024]
// ---------------------------------------------------------------------------
__global__ __launch_bounds__(256) void wsplit_kernel(
    const float* __restrict__ Wk, const float* __restrict__ Wq, const float* __restrict__ Wv,
    short* __restrict__ wbhi, short* __restrict__ wblo)
{
    int i = blockIdx.x * 256 + threadIdx.x;  // 49152 threads, 4 floats each
    int off = i << 2;
    int which = off >> 16;                   // 0..2
    int loc = off & 65535;
    const float* src = (which == 0) ? Wk : (which == 1) ? Wq : Wv;
    float4 v = *(const float4*)(src + loc);
    short h0,h1,h2,h3, l0,l1,l2,l3;
    split_bf16(v.x, h0, l0); split_bf16(v.y, h1, l1);
    split_bf16(v.z, h2, l2); split_bf16(v.w, h3, l3);
    *(s16x4*)(wbhi + off) = (s16x4){h0,h1,h2,h3};
    *(s16x4*)(wblo + off) = (s16x4){l0,l1,l2,l3};
}

// ---------------------------------------------------------------------------
// Kernel 1: QKV projection via split-bf16 MFMA.
// grid (256, 3), block 256 (4 waves). BM=32 rows, 64 cols, BK=64.
// Wave w: rows (w&1)*16, cols (w>>1)*32 (2 col-tiles).
// mode 0 -> k (split bf16 [tok][64]); mode 1 -> q*8 (same); mode 2 -> vT [4][64][2048].
// ---------------------------------------------------------------------------
__global__ __launch_bounds__(256) void proj_mfma(
    const float* __restrict__ x,
    const short* __restrict__ wbhi, const short* __restrict__ wblo,
    short* __restrict__ khi, short* __restrict__ klo,
    short* __restrict__ qhi, short* __restrict__ qlo,
    short* __restrict__ vthi, short* __restrict__ vtlo)
{
    __shared__ __align__(16) short xhi[32][72], xlo[32][72];
    __shared__ __align__(16) short whi[64][72], wlo[64][72];

    const int tid  = threadIdx.x;
    const int w    = tid >> 6;
    const int lane = tid & 63;
    const int g    = lane >> 4;
    const int c    = lane & 15;
    const int mode = blockIdx.y;
    const long rb  = (long)blockIdx.x * 32;

    const short* wsrch = wbhi + mode * 65536;
    const short* wsrcl = wblo + mode * 65536;

    f32x4 acc[2];
    acc[0] = 0; acc[1] = 0;

    const int rowoff = (w & 1) * 16;
    const int coloff = (w >> 1) * 32;

    for (int k0 = 0; k0 < DDIM; k0 += 64) {
        // stage x tile 32x64 fp32 -> split bf16 LDS
        #pragma unroll
        for (int u = 0; u < 2; ++u) {
            int idx = tid + u * 256;           // 512 float4 chunks over 32x16
            int row = idx >> 4, c4 = (idx & 15) << 2;
            float4 xv = *(const float4*)(x + (rb + row) * DDIM + k0 + c4);
            short h0,h1,h2,h3, l0,l1,l2,l3;
            split_bf16(xv.x, h0, l0); split_bf16(xv.y, h1, l1);
            split_bf16(xv.z, h2, l2); split_bf16(xv.w, h3, l3);
            *(s16x4*)&xhi[row][c4] = (s16x4){h0,h1,h2,h3};
            *(s16x4*)&xlo[row][c4] = (s16x4){l0,l1,l2,l3};
        }
        // stage W tile 64x64 bf16 (pre-split)
        #pragma unroll
        for (int u = 0; u < 2; ++u) {
            int idx = tid + u * 256;           // 512 short8 chunks over 64x8
            int row = idx >> 3, c8 = (idx & 7) << 3;
            *(bf16x8*)&whi[row][c8] = *(const bf16x8*)(wsrch + row * DDIM + k0 + c8);
            *(bf16x8*)&wlo[row][c8] = *(const bf16x8*)(wsrcl + row * DDIM + k0 + c8);
        }
        __syncthreads();

        #pragma unroll
        for (int kk = 0; kk < 2; ++kk) {
            bf16x8 ah = *(const bf16x8*)&xhi[rowoff + c][kk*32 + 8*g];
            bf16x8 al = *(const bf16x8*)&xlo[rowoff + c][kk*32 + 8*g];
            #pragma unroll
            for (int ct = 0; ct < 2; ++ct) {
                bf16x8 bh = *(const bf16x8*)&whi[coloff + ct*16 + c][kk*32 + 8*g];
                bf16x8 bl = *(const bf16x8*)&wlo[coloff + ct*16 + c][kk*32 + 8*g];
                acc[ct] = MFMA16(al, bh, acc[ct]);
                acc[ct] = MFMA16(ah, bl, acc[ct]);
                acc[ct] = MFMA16(ah, bh, acc[ct]);
            }
        }
        __syncthreads();
    }

    if (mode < 2) {
        short* oh = (mode == 0) ? khi : qhi;
        short* ol = (mode == 0) ? klo : qlo;
        const float sc = (mode == 0) ? 1.0f : 8.0f;   // fold bug-faithful *sqrt(HS) into q
        #pragma unroll
        for (int ct = 0; ct < 2; ++ct) {
            #pragma unroll
            for (int r = 0; r < 4; ++r) {
                long row = rb + rowoff + 4*g + r;
                float vv = acc[ct][r] * sc;
                short h, lo2; split_bf16(vv, h, lo2);
                oh[row * HSZ + coloff + ct*16 + c] = h;
                ol[row * HSZ + coloff + ct*16 + c] = lo2;
            }
        }
    } else {
        // v: transpose through LDS (reuse whi/wlo), write vT [batch][d][token]
        #pragma unroll
        for (int ct = 0; ct < 2; ++ct) {
            #pragma unroll
            for (int r = 0; r < 4; ++r) {
                short h, lo2; split_bf16(acc[ct][r], h, lo2);
                whi[coloff + ct*16 + c][rowoff + 4*g + r] = h;
                wlo[coloff + ct*16 + c][rowoff + 4*g + r] = lo2;
            }
        }
        __syncthreads();
        int batch = (int)(rb >> 11);
        int t0    = (int)(rb & 2047);
        int d = tid >> 2, t8 = (tid & 3) << 3;   // 64 d-rows x 4 chunks of 8 tokens
        long gofs = ((long)batch * HSZ + d) * TSEQ + t0 + t8;
        *(bf16x8*)(vthi + gofs) = *(const bf16x8*)&whi[d][t8];
        *(bf16x8*)(vtlo + gofs) = *(const bf16x8*)&wlo[d][t8];
    }
}

// ---------------------------------------------------------------------------
// Kernel 2: causal flash attention via split-bf16 MFMA.
// grid 512 (heavy tiles first), block 256 (4 waves). Each block: 16 q-rows.
// Per step: 256 keys split across waves (64 each). K,V fragments direct from
// global (bf16, frag = 8 contiguous elems at row lane&15). P via LDS transpose.
// ---------------------------------------------------------------------------
__global__ __launch_bounds__(256) void attn_mfma(
    const short* __restrict__ qhi, const short* __restrict__ qlo,
    const short* __restrict__ khi, const short* __restrict__ klo,
    const short* __restrict__ vthi, const short* __restrict__ vtlo,
    float* __restrict__ out)
{
    __shared__ __align__(16) short phi[4][16][72], plo[4][16][72];
    __shared__ float smax[4][16], lsum[4][16];
    __shared__ float obuf[3][16][65];

    const int tid  = threadIdx.x;
    const int w    = tid >> 6;
    const int lane = tid & 63;
    const int g    = lane >> 4;
    const int c    = lane & 15;
    const int bid  = blockIdx.x;
    const int batch = bid & 3;
    const int tile  = 127 - (bid >> 2);     // heaviest first
    const int qb0   = tile << 4;
    const long bb   = (long)batch * TSEQ;

    // Q A-fragments (row = c, k = 8g+j), q pre-scaled by 8
    bf16x8 qa[2][2];
    {
        const long qofs = (bb + qb0 + c) * HSZ;
        #pragma unroll
        for (int kk = 0; kk < 2; ++kk) {
            qa[kk][0] = *(const bf16x8*)(qhi + qofs + kk*32 + 8*g);
            qa[kk][1] = *(const bf16x8*)(qlo + qofs + kk*32 + 8*g);
        }
    }

    f32x4 oacc[4];
    #pragma unroll
    for (int dt = 0; dt < 4; ++dt) oacc[dt] = 0;
    float m[4], l[4];
    #pragma unroll
    for (int r = 0; r < 4; ++r) { m[r] = -1e30f; l[r] = 0.0f; }

    const int keylen = (tile + 1) << 4;
    const int nsteps = (keylen + 255) >> 8;

    for (int s = 0; s < nsteps; ++s) {
        const int jbw = (s << 8) + (w << 6);        // this wave's 64-key window
        const bool active = (jbw <= qb0 + 15);

        f32x4 sa[4];
        float mx[4];
        #pragma unroll
        for (int r = 0; r < 4; ++r) mx[r] = -1e30f;

        if (active) {
            // ---- S = Q K^T over this wave's 64 keys (4 col-tiles) ----
            #pragma unroll
            for (int ct = 0; ct < 4; ++ct) sa[ct] = 0;
            #pragma unroll
            for (int kk = 0; kk < 2; ++kk) {
                bf16x8 kbh[4], kbl[4];
                #pragma unroll
                for (int ct = 0; ct < 4; ++ct) {
                    const long kofs = (bb + jbw + ct*16 + c) * HSZ + kk*32 + 8*g;
                    kbh[ct] = *(const bf16x8*)(khi + kofs);
                    kbl[ct] = *(const bf16x8*)(klo + kofs);
                }
                #pragma unroll
                for (int ct = 0; ct < 4; ++ct) {
                    sa[ct] = MFMA16(qa[kk][1], kbh[ct], sa[ct]);
                    sa[ct] = MFMA16(qa[kk][0], kbl[ct], sa[ct]);
                    sa[ct] = MFMA16(qa[kk][0], kbh[ct], sa[ct]);
                }
            }
            // causal mask (only near the diagonal)
            if (jbw + 63 > qb0) {
                #pragma unroll
                for (int ct = 0; ct < 4; ++ct) {
                    int key = jbw + ct*16 + c;
                    #pragma unroll
                    for (int r = 0; r < 4; ++r)
                        if (key > qb0 + 4*g + r) sa[ct][r] = -1e30f;
                }
            }
            // per-wave partial row max (reduce over the 16 col-lanes)
            #pragma unroll
            for (int r = 0; r < 4; ++r)
                mx[r] = fmaxf(fmaxf(sa[0][r], sa[1][r]), fmaxf(sa[2][r], sa[3][r]));
            #pragma unroll
            for (int off = 1; off <= 8; off <<= 1) {
                #pragma unroll
                for (int r = 0; r < 4; ++r)
                    mx[r] = fmaxf(mx[r], __shfl_xor(mx[r], off));
            }
        }
        if (c == 0) {
            #pragma unroll
            for (int r = 0; r < 4; ++r) smax[w][4*g + r] = mx[r];
        }
        __syncthreads();   // B1: stats max

        float mn[4];
        #pragma unroll
        for (int r = 0; r < 4; ++r) {
            float cm = fmaxf(fmaxf(smax[0][4*g+r], smax[1][4*g+r]),
                             fmaxf(smax[2][4*g+r], smax[3][4*g+r]));
            mn[r] = fmaxf(m[r], cm);
        }

        float rs[4] = {0.f, 0.f, 0.f, 0.f};
        if (active) {
            #pragma unroll
            for (int ct = 0; ct < 4; ++ct) {
                #pragma unroll
                for (int r = 0; r < 4; ++r) {
                    float p = __expf(sa[ct][r] - mn[r]);
                    sa[ct][r] = p;
                    rs[r] += p;
                }
            }
            #pragma unroll
            for (int off = 1; off <= 8; off <<= 1) {
                #pragma unroll
                for (int r = 0; r < 4; ++r) rs[r] += __shfl_xor(rs[r], off);
            }
            // split P -> LDS (C-layout write; A-layout read after barrier)
            #pragma unroll
            for (int ct = 0; ct < 4; ++ct) {
                #pragma unroll
                for (int r = 0; r < 4; ++r) {
                    short h, lo2; split_bf16(sa[ct][r], h, lo2);
                    phi[w][4*g + r][ct*16 + c] = h;
                    plo[w][4*g + r][ct*16 + c] = lo2;
                }
            }
        }
        if (c == 0) {
            #pragma unroll
            for (int r = 0; r < 4; ++r) lsum[w][4*g + r] = rs[r];
        }
        __syncthreads();   // B2: stats sum + P visibility

        float fsc[4];
        #pragma unroll
        for (int r = 0; r < 4; ++r) {
            float rsum = lsum[0][4*g+r] + lsum[1][4*g+r] + lsum[2][4*g+r] + lsum[3][4*g+r];
            fsc[r] = __expf(m[r] - mn[r]);
            l[r] = l[r] * fsc[r] + rsum;
            m[r] = mn[r];
        }
        #pragma unroll
        for (int dt = 0; dt < 4; ++dt) {
            #pragma unroll
            for (int r = 0; r < 4; ++r) oacc[dt][r] *= fsc[r];
        }

        if (active) {
            // ---- O += P V over this wave's 64 keys ----
            #pragma unroll
            for (int kk = 0; kk < 2; ++kk) {
                bf16x8 pah = *(const bf16x8*)&phi[w][c][kk*32 + 8*g];
                bf16x8 pal = *(const bf16x8*)&plo[w][c][kk*32 + 8*g];
                bf16x8 vbh[4], vbl[4];
                #pragma unroll
                for (int dt = 0; dt < 4; ++dt) {
                    const long vofs = ((long)(batch*HSZ + dt*16 + c)) * TSEQ + jbw + kk*32 + 8*g;
                    vbh[dt] = *(const bf16x8*)(vthi + vofs);
                    vbl[dt] = *(const bf16x8*)(vtlo + vofs);
                }
                #pragma unroll
                for (int dt = 0; dt < 4; ++dt) {
                    oacc[dt] = MFMA16(pal, vbh[dt], oacc[dt]);
                    oacc[dt] = MFMA16(pah, vbl[dt], oacc[dt]);
                    oacc[dt] = MFMA16(pah, vbh[dt], oacc[dt]);
                }
            }
        }
    }

    // combine the 4 waves' partial O
    if (w > 0) {
        #pragma unroll
        for (int dt = 0; dt < 4; ++dt) {
            #pragma unroll
            for (int r = 0; r < 4; ++r)
                obuf[w-1][4*g + r][dt*16 + c] = oacc[dt][r];
        }
    }
    __syncthreads();
    if (w == 0) {
        #pragma unroll
        for (int r = 0; r < 4; ++r) {
            float linv = 1.0f / l[r];
            #pragma unroll
            for (int dt = 0; dt < 4; ++dt) {
                float vv = oacc[dt][r] + obuf[0][4*g+r][dt*16+c]
                         + obuf[1][4*g+r][dt*16+c] + obuf[2][4*g+r][dt*16+c];
                out[(bb + qb0 + 4*g + r) * HSZ + dt*16 + c] = vv * linv;
            }
        }
    }
}

// ---------------------------------------------------------------------------
extern "C" void kernel_launch(void* const* d_in, const int* in_sizes, int n_in,
                              void* d_out, int out_size, void* d_ws, size_t ws_size,
                              hipStream_t stream) {
    const float* x  = (const float*)d_in[0];
    const float* Wk = (const float*)d_in[1];
    const float* Wq = (const float*)d_in[2];
    const float* Wv = (const float*)d_in[3];
    float* out = (float*)d_out;

    short* ws = (short*)d_ws;
    const size_t SEG = (size_t)NROWS * HSZ;   // 524288 elements
    short* khi  = ws;
    short* klo  = ws + SEG;
    short* qhi  = ws + 2*SEG;
    short* qlo  = ws + 3*SEG;
    short* vthi = ws + 4*SEG;                 // [4][64][2048]
    short* vtlo = ws + 5*SEG;
    short* wbhi = ws + 6*SEG;                 // [3][64][1024]
    short* wblo = wbhi + 3*HSZ*DDIM;

    wsplit_kernel<<<192, 256, 0, stream>>>(Wk, Wq, Wv, wbhi, wblo);
    proj_mfma<<<dim3(256, 3), 256, 0, stream>>>(x, wbhi, wblo,
                                                khi, klo, qhi, qlo, vthi, vtlo);
    attn_mfma<<<NB * (TSEQ / 16), 256, 0, stream>>>(qhi, qlo, khi, klo, vthi, vtlo, out);
}

// Round 4
// 148.812 us; speedup vs baseline: 1.7320x; 1.0208x over previous
//
#include <hip/hip_runtime.h>

#define TSEQ 2048
#define DDIM 1024
#define HSZ  64
#define NB   4
#define NROWS (NB * TSEQ)

typedef short bf16x8 __attribute__((ext_vector_type(8)));
typedef short s16x4  __attribute__((ext_vector_type(4)));
typedef float f32x4  __attribute__((ext_vector_type(4)));
typedef unsigned int u32;
typedef unsigned int u32x4 __attribute__((ext_vector_type(4)));

#define MFMA16(a, b, c) __builtin_amdgcn_mfma_f32_16x16x32_bf16((a), (b), (c), 0, 0, 0)

// Split fp32 into bf16 hi (round-to-nearest-even) + bf16 lo (exact residual, truncated).
__device__ inline void split_rn(float f, short& hi, short& lo) {
    u32 u = __builtin_bit_cast(u32, f);
    u32 rr = (u + 0x7fffu + ((u >> 16) & 1u)) & 0xffff0000u;
    hi = (short)(rr >> 16);
    float fh = __builtin_bit_cast(float, rr);
    float fl = f - fh;
    lo = (short)(__builtin_bit_cast(u32, fl) >> 16);
}

__device__ inline void gload_lds16(const void* g, void* l) {
    __builtin_amdgcn_global_load_lds((const __attribute__((address_space(1))) void*)g,
                                     (__attribute__((address_space(3))) void*)l, 16, 0, 0);
}

// ---------------------------------------------------------------------------
// Kernel 0: split W (fp32 [3*64][1024]) -> bf16 hi/lo, K-SWIZZLED within each
// 64-elem k-block: dst_k = (k&~63) | ((k&63) ^ ((row&7)<<3)). proj's
// global_load_lds stages rows linearly; reads XOR the same pattern back.
// ---------------------------------------------------------------------------
__global__ __launch_bounds__(256) void wsplit_kernel(
    const float* __restrict__ Wk, const float* __restrict__ Wq, const float* __restrict__ Wv,
    short* __restrict__ wbhi, short* __restrict__ wblo)
{
    int i = blockIdx.x * 256 + threadIdx.x;      // 49152 threads, 4 floats each
    int off = i << 2;                            // flat elem in [192][1024]
    int which = off >> 16;
    int loc = off & 65535;
    const float* src = (which == 0) ? Wk : (which == 1) ? Wq : Wv;
    float4 v = *(const float4*)(src + loc);
    int row = off >> 10;                         // 0..191
    int k = off & 1023;
    int kd = (k & ~63) | ((k & 63) ^ ((row & 7) << 3));
    int dst = (row << 10) | kd;                  // 4-aligned (k mult of 4, xor bits 3..5)
    short h0,h1,h2,h3, l0,l1,l2,l3;
    split_rn(v.x, h0, l0); split_rn(v.y, h1, l1);
    split_rn(v.z, h2, l2); split_rn(v.w, h3, l3);
    *(s16x4*)(wbhi + dst) = (s16x4){h0,h1,h2,h3};
    *(s16x4*)(wblo + dst) = (s16x4){l0,l1,l2,l3};
}

// ---------------------------------------------------------------------------
// Kernel 1: fused QKV projection. grid 256, block 512 (8 waves).
// Block: 32 tokens x all 192 cols (k|q|v). x split-staged once per K-step;
// W staged via global_load_lds from pre-swizzled global; swizzled LDS reads.
// Wave w: rows (w&1)*16, col group (w>>1)*48 (3 col-tiles of 16).
// Outputs: khi/klo, qhi/qlo (x8) as [8192][64]; v transposed -> vthi/vtlo [4][64][2048].
// ---------------------------------------------------------------------------
__global__ __launch_bounds__(512) void proj_mfma(
    const float* __restrict__ x,
    const short* __restrict__ wbhi, const short* __restrict__ wblo,
    short* __restrict__ khi, short* __restrict__ klo,
    short* __restrict__ qhi, short* __restrict__ qlo,
    short* __restrict__ vthi, short* __restrict__ vtlo)
{
    __shared__ __align__(16) short xhi[32][72], xlo[32][72];
    __shared__ __align__(16) short whi[192 * 64], wlo[192 * 64];   // linear, swizzled content

    const int tid  = threadIdx.x;
    const int w    = tid >> 6;
    const int lane = tid & 63;
    const int g    = lane >> 4;
    const int c    = lane & 15;
    const int rowoff = (w & 1) * 16;
    const int colgrp = w >> 1;                    // 0..3
    const long rb  = (long)blockIdx.x * 32;

    f32x4 acc[3];
    acc[0] = 0; acc[1] = 0; acc[2] = 0;

    for (int k0 = 0; k0 < DDIM; k0 += 64) {
        // x tile 32x64 fp32 -> split bf16 LDS (one float4 per thread)
        {
            int row = tid >> 4, c4 = (tid & 15) << 2;
            float4 xv = *(const float4*)(x + (rb + row) * DDIM + k0 + c4);
            short h0,h1,h2,h3, l0,l1,l2,l3;
            split_rn(xv.x, h0, l0); split_rn(xv.y, h1, l1);
            split_rn(xv.z, h2, l2); split_rn(xv.w, h3, l3);
            *(s16x4*)&xhi[row][c4] = (s16x4){h0,h1,h2,h3};
            *(s16x4*)&xlo[row][c4] = (s16x4){l0,l1,l2,l3};
        }
        // W tile [192][64] hi+lo via async global->LDS (3 chunks per wave per array)
        #pragma unroll
        for (int u = 0; u < 3; ++u) {
            int hchunk = w * 3 + u;                   // 0..23
            int sidx = hchunk * 512 + lane * 8;       // short index in tile
            int trow = sidx >> 6, tk = sidx & 63;
            gload_lds16(wbhi + trow * DDIM + k0 + tk, whi + hchunk * 512);
            gload_lds16(wblo + trow * DDIM + k0 + tk, wlo + hchunk * 512);
        }
        __syncthreads();

        #pragma unroll
        for (int kk = 0; kk < 2; ++kk) {
            bf16x8 ah = *(const bf16x8*)&xhi[rowoff + c][kk*32 + 8*g];
            bf16x8 al = *(const bf16x8*)&xlo[rowoff + c][kk*32 + 8*g];
            #pragma unroll
            for (int t = 0; t < 3; ++t) {
                int wr = colgrp * 48 + t * 16 + c;
                int koff = (kk*32 + 8*g) ^ ((wr & 7) << 3);
                bf16x8 bh = *(const bf16x8*)&whi[wr * 64 + koff];
                bf16x8 bl = *(const bf16x8*)&wlo[wr * 64 + koff];
                acc[t] = MFMA16(al, bh, acc[t]);
                acc[t] = MFMA16(ah, bl, acc[t]);
                acc[t] = MFMA16(ah, bh, acc[t]);
            }
        }
        __syncthreads();
    }

    __syncthreads();
    // epilogue: k/q direct; v transposed through LDS (reuse xhi/xlo as [64][36])
    short (*vtrh)[36] = (short(*)[36])(&xhi[0][0]);
    short (*vtrl)[36] = (short(*)[36])(&xlo[0][0]);
    const int batch = (int)(rb >> 11);
    const int t0 = (int)(rb & 2047);
    #pragma unroll
    for (int t = 0; t < 3; ++t) {
        int col16 = colgrp * 48 + t * 16;
        int mode = col16 >> 6;
        int lcol = col16 - (mode << 6) + c;
        if (mode < 2) {
            short* oh = mode ? qhi : khi;
            short* ol = mode ? qlo : klo;
            const float sc = mode ? 8.0f : 1.0f;   // fold bug-faithful *sqrt(HS) into q
            #pragma unroll
            for (int r = 0; r < 4; ++r) {
                long row = rb + rowoff + 4*g + r;
                short h, lo2; split_rn(acc[t][r] * sc, h, lo2);
                oh[row * HSZ + lcol] = h;
                ol[row * HSZ + lcol] = lo2;
            }
        } else {
            #pragma unroll
            for (int r = 0; r < 4; ++r) {
                short h, lo2; split_rn(acc[t][r], h, lo2);
                vtrh[lcol][rowoff + 4*g + r] = h;
                vtrl[lcol][rowoff + 4*g + r] = lo2;
            }
        }
    }
    __syncthreads();
    {
        int d = tid >> 3, t4 = (tid & 7) << 2;
        long gofs = ((long)(batch * HSZ + d)) * TSEQ + t0 + t4;
        *(s16x4*)(vthi + gofs) = *(const s16x4*)&vtrh[d][t4];
        *(s16x4*)(vtlo + gofs) = *(const s16x4*)&vtrl[d][t4];
    }
}

// ---------------------------------------------------------------------------
// Kernel 2: causal flash attention, barrier-free main loop.
// grid 512, block 512 (8 waves). Block = 16 q-rows; wave w independently
// processes key windows jb = s*512 + w*64 with per-wave online softmax
// (swapped QK^T: lane owns q-row c); cross-wave merge once at the end.
// XCD-bijective block remap; odd/even tile striping balances XCD pairs.
// P store layout NOTE: swapped QK^T puts P[qrow=c][key=t*16+4g+r] in each
// lane, so the store must be pbuf[w][c][t*16+4g+r] (qrow row, key col) for
// the PV A-fragment read pbuf[w][c][kk*32+8g+j] to be layout-correct.
// ---------------------------------------------------------------------------
__global__ __launch_bounds__(512, 4) void attn_mfma(
    const short* __restrict__ qhi, const short* __restrict__ qlo,
    const short* __restrict__ khi, const short* __restrict__ klo,
    const short* __restrict__ vthi, const short* __restrict__ vtlo,
    float* __restrict__ out)
{
    __shared__ __align__(16) u32  pbuf[8][16][68];
    __shared__ float obuf[7][16][68];
    __shared__ float mlbuf[8][16][2];

    const int tid  = threadIdx.x;
    const int w    = tid >> 6;
    const int lane = tid & 63;
    const int g    = lane >> 4;
    const int c    = lane & 15;

    const int bid   = blockIdx.x;
    const int work  = ((bid & 7) << 6) | (bid >> 3);   // XCD x -> contiguous work chunk
    const int batch = work >> 7;                        // 2 XCD chunks per batch
    const int rank  = work & 127;
    const int tile  = (rank < 64) ? (127 - 2*rank) : (126 - 2*(rank - 64));
    const int qb0   = tile << 4;
    const long bb   = (long)batch * TSEQ;

    // Q fragments (B-operand of swapped QK^T): row = c (q-row), k = kk*32+8g+j
    bf16x8 qh[2], ql[2];
    {
        const long qofs = (bb + qb0 + c) * HSZ;
        #pragma unroll
        for (int kk = 0; kk < 2; ++kk) {
            qh[kk] = *(const bf16x8*)(qhi + qofs + kk*32 + 8*g);
            ql[kk] = *(const bf16x8*)(qlo + qofs + kk*32 + 8*g);
        }
    }

    f32x4 oacc[4];
    #pragma unroll
    for (int dt = 0; dt < 4; ++dt) oacc[dt] = 0;
    float m = -1e30f, l = 0.0f;                 // for q-row qb0 + c (dup over g)

    const int lastkey = qb0 + 15;
    if (64 * w <= lastkey) {
        const int nsteps = ((lastkey - 64 * w) >> 9) + 1;
        for (int s = 0; s < nsteps; ++s) {
            const int jb = (s << 9) + (w << 6);
            // ---- S^T tile: mfma(A=K, B=Q): lane -> S[qrow=c][key = jb+16t+4g+r] ----
            f32x4 sa[4];
            sa[0] = 0; sa[1] = 0; sa[2] = 0; sa[3] = 0;
            #pragma unroll
            for (int kk = 0; kk < 2; ++kk) {
                bf16x8 kb_h[4], kb_l[4];
                #pragma unroll
                for (int t = 0; t < 4; ++t) {
                    const long kofs = (bb + jb + t*16 + c) * HSZ + kk*32 + 8*g;
                    kb_h[t] = *(const bf16x8*)(khi + kofs);
                    kb_l[t] = *(const bf16x8*)(klo + kofs);
                }
                #pragma unroll
                for (int t = 0; t < 4; ++t) {
                    sa[t] = MFMA16(kb_h[t], ql[kk], sa[t]);
                    sa[t] = MFMA16(kb_l[t], qh[kk], sa[t]);
                    sa[t] = MFMA16(kb_h[t], qh[kk], sa[t]);
                }
            }
            // causal mask (windows never start past the diagonal: jb <= qb0)
            if (jb + 63 > qb0) {
                #pragma unroll
                for (int t = 0; t < 4; ++t) {
                    const int kb0 = jb + t*16 + 4*g;
                    #pragma unroll
                    for (int r = 0; r < 4; ++r)
                        if (kb0 + r > qb0 + c) sa[t][r] = -1e30f;
                }
            }
            // ---- per-lane online softmax for q-row c ----
            float mx = sa[0][0];
            #pragma unroll
            for (int t = 0; t < 4; ++t)
                #pragma unroll
                for (int r = 0; r < 4; ++r) mx = fmaxf(mx, sa[t][r]);
            mx = fmaxf(mx, __shfl_xor(mx, 16));
            mx = fmaxf(mx, __shfl_xor(mx, 32));
            const float mn = fmaxf(m, mx);
            float rs = 0.0f;
            #pragma unroll
            for (int t = 0; t < 4; ++t) {
                #pragma unroll
                for (int r = 0; r < 4; ++r) {
                    float p = __expf(sa[t][r] - mn);
                    rs += p;
                    short h, lo2; split_rn(p, h, lo2);
                    pbuf[w][c][t*16 + 4*g + r] =
                        (u32)(unsigned short)h | ((u32)(unsigned short)lo2 << 16);
                }
            }
            rs += __shfl_xor(rs, 16);
            rs += __shfl_xor(rs, 32);
            const float fs = __expf(m - mn);
            l = l * fs + rs;
            m = mn;
            float fr[4];
            #pragma unroll
            for (int r = 0; r < 4; ++r) fr[r] = __shfl(fs, (g << 4) + 4*g + r);
            #pragma unroll
            for (int dt = 0; dt < 4; ++dt) {
                oacc[dt][0] *= fr[0]; oacc[dt][1] *= fr[1];
                oacc[dt][2] *= fr[2]; oacc[dt][3] *= fr[3];
            }
            // ---- O += P V (A-frag of P from per-wave LDS, no barrier needed) ----
            #pragma unroll
            for (int kk = 0; kk < 2; ++kk) {
                u32x4 pw0 = *(const u32x4*)&pbuf[w][c][kk*32 + 8*g];
                u32x4 pw1 = *(const u32x4*)&pbuf[w][c][kk*32 + 8*g + 4];
                u32x4 th, tl;
                th[0] = (pw0[0] & 0xffffu) | (pw0[1] << 16);
                tl[0] = (pw0[0] >> 16)    | (pw0[1] & 0xffff0000u);
                th[1] = (pw0[2] & 0xffffu) | (pw0[3] << 16);
                tl[1] = (pw0[2] >> 16)    | (pw0[3] & 0xffff0000u);
                th[2] = (pw1[0] & 0xffffu) | (pw1[1] << 16);
                tl[2] = (pw1[0] >> 16)    | (pw1[1] & 0xffff0000u);
                th[3] = (pw1[2] & 0xffffu) | (pw1[3] << 16);
                tl[3] = (pw1[2] >> 16)    | (pw1[3] & 0xffff0000u);
                bf16x8 pah = __builtin_bit_cast(bf16x8, th);
                bf16x8 pal = __builtin_bit_cast(bf16x8, tl);
                bf16x8 vb_h[4], vb_l[4];
                #pragma unroll
                for (int dt = 0; dt < 4; ++dt) {
                    const long vofs = ((long)(batch * HSZ + dt*16 + c)) * TSEQ + jb + kk*32 + 8*g;
                    vb_h[dt] = *(const bf16x8*)(vthi + vofs);
                    vb_l[dt] = *(const bf16x8*)(vtlo + vofs);
                }
                #pragma unroll
                for (int dt = 0; dt < 4; ++dt) {
                    oacc[dt] = MFMA16(pal, vb_h[dt], oacc[dt]);
                    oacc[dt] = MFMA16(pah, vb_l[dt], oacc[dt]);
                    oacc[dt] = MFMA16(pah, vb_h[dt], oacc[dt]);
                }
            }
        }
    }

    // ---- cross-wave merge ----
    if (lane < 16) { mlbuf[w][lane][0] = m; mlbuf[w][lane][1] = l; }
    if (w > 0) {
        #pragma unroll
        for (int dt = 0; dt < 4; ++dt)
            #pragma unroll
            for (int r = 0; r < 4; ++r)
                obuf[w-1][4*g + r][dt*16 + c] = oacc[dt][r];
    }
    __syncthreads();
    if (w == 0) {
        #pragma unroll
        for (int r = 0; r < 4; ++r) {
            const int row = 4*g + r;
            float ms = mlbuf[0][row][0];
            #pragma unroll
            for (int wv = 1; wv < 8; ++wv) ms = fmaxf(ms, mlbuf[wv][row][0]);
            float ls = 0.0f; float fw[8];
            #pragma unroll
            for (int wv = 0; wv < 8; ++wv) {
                fw[wv] = __expf(mlbuf[wv][row][0] - ms);
                ls += mlbuf[wv][row][1] * fw[wv];
            }
            const float linv = 1.0f / ls;
            #pragma unroll
            for (int dt = 0; dt < 4; ++dt) {
                float val = oacc[dt][r] * fw[0];
                #pragma unroll
                for (int wv = 1; wv < 8; ++wv) val += obuf[wv-1][row][dt*16 + c] * fw[wv];
                out[(bb + qb0 + row) * HSZ + dt*16 + c] = val * linv;
            }
        }
    }
}

// ---------------------------------------------------------------------------
extern "C" void kernel_launch(void* const* d_in, const int* in_sizes, int n_in,
                              void* d_out, int out_size, void* d_ws, size_t ws_size,
                              hipStream_t stream) {
    const float* x  = (const float*)d_in[0];
    const float* Wk = (const float*)d_in[1];
    const float* Wq = (const float*)d_in[2];
    const float* Wv = (const float*)d_in[3];
    float* out = (float*)d_out;

    short* ws = (short*)d_ws;
    const size_t SEG = (size_t)NROWS * HSZ;   // 524288 elements
    short* khi  = ws;
    short* klo  = ws + SEG;
    short* qhi  = ws + 2*SEG;
    short* qlo  = ws + 3*SEG;
    short* vthi = ws + 4*SEG;                 // [4][64][2048]
    short* vtlo = ws + 5*SEG;
    short* wbhi = ws + 6*SEG;                 // [3][64][1024], k-swizzled
    short* wblo = wbhi + 3*HSZ*DDIM;

    wsplit_kernel<<<192, 256, 0, stream>>>(Wk, Wq, Wv, wbhi, wblo);
    proj_mfma<<<256, 512, 0, stream>>>(x, wbhi, wblo, khi, klo, qhi, qlo, vthi, vtlo);
    attn_mfma<<<512, 512, 0, stream>>>(qhi, qlo, khi, klo, vthi, vtlo, out);
}